// Round 1
// baseline (697.964 us; speedup 1.0000x reference)
//
#include <hip/hip_runtime.h>

#define B   32
#define S   1024
#define D   512
#define D2  1024
#define D3  1536
#define D5  2560
#define V   50000
#define VO  49000

__device__ __forceinline__ float fast_tanh(float x){
    float e = __expf(2.0f * x);
    return 1.0f - __fdividef(2.0f, e + 1.0f);
}

// K1: dec_op1[b][j] = sum_k [h;c][b][k] * W_dec[j][k] + b_dec[j]
__global__ void k1_decop1(const float* __restrict__ h, const float* __restrict__ c,
                          const float* __restrict__ W, const float* __restrict__ bias,
                          float* __restrict__ out){
    int b = blockIdx.x;
    int j = blockIdx.y * 256 + threadIdx.x;
    __shared__ float sd[D2];
    for (int i = threadIdx.x; i < D; i += 256){
        sd[i]     = h[b * D + i];
        sd[D + i] = c[b * D + i];
    }
    __syncthreads();
    const float4* Wr  = (const float4*)(W + (size_t)j * D2);
    const float4* sd4 = (const float4*)sd;
    float acc = 0.f;
    #pragma unroll 8
    for (int k = 0; k < D2 / 4; ++k){
        float4 w = Wr[k]; float4 x = sd4[k];
        acc += w.x * x.x + w.y * x.y + w.z * x.z + w.w * x.w;
    }
    out[b * D2 + j] = acc + bias[j];
}

// K2a: attn logit[b][s] = sum_d tanh(enc1[b][s][d] + dec_op1[b][d]) * w_attn[d]
__global__ void k2a_logit(const float* __restrict__ enc1, const float* __restrict__ dop1,
                          const float* __restrict__ wat, float* __restrict__ lg){
    int b = blockIdx.x;
    int wave = threadIdx.x >> 6, lane = threadIdx.x & 63;
    int s = blockIdx.y * 4 + wave;
    __shared__ float sd[D2], sw[D2];
    for (int i = threadIdx.x; i < D2; i += 256){
        sd[i] = dop1[b * D2 + i];
        sw[i] = wat[i];
    }
    __syncthreads();
    const float4* row = (const float4*)(enc1 + ((size_t)b * S + s) * D2);
    const float4* sd4 = (const float4*)sd;
    const float4* sw4 = (const float4*)sw;
    float acc = 0.f;
    #pragma unroll
    for (int i = 0; i < 4; ++i){
        int k4 = i * 64 + lane;
        float4 e = row[k4]; float4 dv = sd4[k4]; float4 wv = sw4[k4];
        acc += fast_tanh(e.x + dv.x) * wv.x + fast_tanh(e.y + dv.y) * wv.y
             + fast_tanh(e.z + dv.z) * wv.z + fast_tanh(e.w + dv.w) * wv.w;
    }
    #pragma unroll
    for (int off = 32; off > 0; off >>= 1) acc += __shfl_down(acc, off, 64);
    if (lane == 0) lg[b * S + s] = acc;
}

// K2b: masked softmax + renormalize -> attn (output 1)
__global__ void k2b_attnsm(const float* __restrict__ lg, const int* __restrict__ src,
                           float* __restrict__ attn){
    int b = blockIdx.x, t = threadIdx.x;
    __shared__ float red[256];
    float l[4];
    float m = -1e30f;
    #pragma unroll
    for (int i = 0; i < 4; ++i){ l[i] = lg[b * S + t + i * 256]; m = fmaxf(m, l[i]); }
    red[t] = m; __syncthreads();
    for (int o = 128; o > 0; o >>= 1){
        if (t < o) red[t] = fmaxf(red[t], red[t + o]);
        __syncthreads();
    }
    m = red[0]; __syncthreads();
    float e[4]; float sum = 0.f;
    #pragma unroll
    for (int i = 0; i < 4; ++i){
        int s = t + i * 256;
        bool keep = src[b * S + s] != 0;
        e[i] = keep ? __expf(l[i] - m) : 0.f;
        sum += e[i];
    }
    red[t] = sum; __syncthreads();
    for (int o = 128; o > 0; o >>= 1){
        if (t < o) red[t] += red[t + o];
        __syncthreads();
    }
    float inv = 1.0f / red[0];
    #pragma unroll
    for (int i = 0; i < 4; ++i) attn[b * S + t + i * 256] = e[i] * inv;
}

// K2c: context partials over s-splits: part[b][sp][d] = sum_{s in split} attn*enc
__global__ void k2c_ctxpart(const float* __restrict__ enc, const float* __restrict__ attn,
                            float* __restrict__ part){
    int b = blockIdx.x, sp = blockIdx.y, t = threadIdx.x;
    __shared__ float sa[32];
    if (t < 32) sa[t] = attn[b * S + sp * 32 + t];
    __syncthreads();
    const float4* base = (const float4*)(enc + ((size_t)b * S + sp * 32) * D2);
    float4 acc = make_float4(0.f, 0.f, 0.f, 0.f);
    #pragma unroll 4
    for (int s = 0; s < 32; ++s){
        float a = sa[s];
        float4 e = base[s * (D2 / 4) + t];
        acc.x += a * e.x; acc.y += a * e.y; acc.z += a * e.z; acc.w += a * e.w;
    }
    ((float4*)(part + ((size_t)(b * 32 + sp)) * D2))[t] = acc;
}

// K2d: reduce partials + batchnorm -> context (output 2)
__global__ void k2d_ctxbn(const float* __restrict__ part, const float* __restrict__ gamma,
                          const float* __restrict__ beta, const float* __restrict__ mean,
                          const float* __restrict__ var, float* __restrict__ ctx){
    int b = blockIdx.x, t = threadIdx.x;
    float4 acc = make_float4(0.f, 0.f, 0.f, 0.f);
    for (int sp = 0; sp < 32; ++sp){
        float4 p = ((const float4*)(part + ((size_t)(b * 32 + sp)) * D2))[t];
        acc.x += p.x; acc.y += p.y; acc.z += p.z; acc.w += p.w;
    }
    float4 g  = ((const float4*)gamma)[t];
    float4 be = ((const float4*)beta)[t];
    float4 mn = ((const float4*)mean)[t];
    float4 vr = ((const float4*)var)[t];
    acc.x = (acc.x - mn.x) * rsqrtf(vr.x + 1e-5f) * g.x + be.x;
    acc.y = (acc.y - mn.y) * rsqrtf(vr.y + 1e-5f) * g.y + be.y;
    acc.z = (acc.z - mn.z) * rsqrtf(vr.z + 1e-5f) * g.z + be.z;
    acc.w = (acc.w - mn.w) * rsqrtf(vr.w + 1e-5f) * g.w + be.w;
    ((float4*)(ctx + (size_t)b * D2))[t] = acc;
}

// K3: hidden[b][j] = sum_k [dec_output;context][b][k] * W_v1[j][k] + b_v1[j]
__global__ void k3_hidden(const float* __restrict__ dec_out, const float* __restrict__ ctx,
                          const float* __restrict__ W1, const float* __restrict__ b1,
                          float* __restrict__ hid){
    int b = blockIdx.x;
    int j = blockIdx.y * 256 + threadIdx.x;
    __shared__ float st[D3];
    for (int i = threadIdx.x; i < D;  i += 256) st[i]     = dec_out[b * D + i];
    for (int i = threadIdx.x; i < D2; i += 256) st[D + i] = ctx[b * D2 + i];
    __syncthreads();
    const float4* Wr  = (const float4*)(W1 + (size_t)j * D3);
    const float4* st4 = (const float4*)st;
    float acc = 0.f;
    #pragma unroll 8
    for (int k = 0; k < D3 / 4; ++k){
        float4 w = Wr[k]; float4 x = st4[k];
        acc += w.x * x.x + w.y * x.y + w.z * x.z + w.w * x.w;
    }
    hid[b * D + j] = acc + b1[j];
}

// K3b: p_gen[b] = sigmoid([ctx;h;c;dec_inp] . W_p + b_p)
__global__ void k3b_pgen(const float* __restrict__ ctx, const float* __restrict__ h,
                         const float* __restrict__ c, const float* __restrict__ di,
                         const float* __restrict__ Wp, const float* __restrict__ bp,
                         float* __restrict__ pg){
    int b = blockIdx.x, t = threadIdx.x;
    float acc = 0.f;
    for (int k = t; k < D5; k += 256){
        float x;
        if (k < D2)            x = ctx[b * D2 + k];
        else if (k < D2 + D)   x = h[b * D + (k - D2)];
        else if (k < 2 * D2)   x = c[b * D + (k - D2 - D)];
        else                   x = di[b * D + (k - 2 * D2)];
        acc += x * Wp[k];
    }
    __shared__ float red[256];
    red[t] = acc; __syncthreads();
    for (int o = 128; o > 0; o >>= 1){
        if (t < o) red[t] += red[t + o];
        __syncthreads();
    }
    if (t == 0){
        float z = red[0] + bp[0];
        pg[b] = 1.0f / (1.0f + __expf(-z));
    }
}

// K4: logits[b][v] += sum_{k in half} hidden[b][k] * W_v2[v][k]  (k-split x2, atomic)
__global__ __launch_bounds__(256) void k4_logits(const float* __restrict__ W2,
                                                 const float* __restrict__ hid,
                                                 float* __restrict__ lg){
    int v = blockIdx.x * 256 + threadIdx.x;
    int kh = blockIdx.y;
    if (v >= VO) return;
    int k0 = kh * (D / 2);
    const float4* wr = (const float4*)(W2 + (size_t)v * D + k0);
    float acc[B];
    #pragma unroll
    for (int b = 0; b < B; ++b) acc[b] = 0.f;
    #pragma unroll 2
    for (int kk = 0; kk < 64; ++kk){
        float4 w = wr[kk];
        int k = k0 + kk * 4;
        #pragma unroll
        for (int b = 0; b < B; ++b){
            const float4 hb = *(const float4*)(hid + b * D + k);
            acc[b] += w.x * hb.x + w.y * hb.y + w.z * hb.z + w.w * hb.w;
        }
    }
    #pragma unroll
    for (int b = 0; b < B; ++b) atomicAdd(&lg[(size_t)b * VO + v], acc[b]);
}

// K5a: per-b online softmax over 49000 logits -> p_final = p_gen * p_vocab, pad zeros
__global__ void k5a_vocab(const float* __restrict__ lg, const float* __restrict__ b2,
                          const float* __restrict__ pg, float* __restrict__ pf){
    int b = blockIdx.x, t = threadIdx.x;
    float m = -1e30f, sum = 0.f;
    for (int v = t; v < VO; v += 256){
        float l = lg[(size_t)b * VO + v] + b2[v];
        float nm = fmaxf(m, l);
        sum = sum * __expf(m - nm) + __expf(l - nm);
        m = nm;
    }
    __shared__ float sm[256], ss[256];
    sm[t] = m; ss[t] = sum; __syncthreads();
    for (int o = 128; o > 0; o >>= 1){
        if (t < o){
            float m1 = sm[t], m2 = sm[t + o];
            float M = fmaxf(m1, m2);
            ss[t] = ss[t] * __expf(m1 - M) + ss[t + o] * __expf(m2 - M);
            sm[t] = M;
        }
        __syncthreads();
    }
    float M = sm[0];
    float scale = pg[b] / ss[0];
    for (int v = t; v < VO; v += 256){
        float l = lg[(size_t)b * VO + v] + b2[v];
        pf[(size_t)b * V + v] = scale * __expf(l - M);
    }
    for (int v = VO + t; v < V; v += 256) pf[(size_t)b * V + v] = 0.f;
}

// K5b: scatter add (1-p_gen)*attn at src indices
__global__ void k5b_scatter(const int* __restrict__ src, const float* __restrict__ attn,
                            const float* __restrict__ pg, float* __restrict__ pf){
    int b = blockIdx.x, t = threadIdx.x;
    float c1 = 1.0f - pg[b];
    for (int s = t; s < S; s += 256){
        int idx = src[b * S + s];
        atomicAdd(&pf[(size_t)b * V + idx], c1 * attn[b * S + s]);
    }
}

// K5c: p_final += (p_final == 0) * 1e-12
__global__ void k5c_eps(float* __restrict__ pf, int n){
    int i = blockIdx.x * 256 + threadIdx.x;
    if (i < n && pf[i] == 0.0f) pf[i] = 1e-12f;
}

extern "C" void kernel_launch(void* const* d_in, const int* in_sizes, int n_in,
                              void* d_out, int out_size, void* d_ws, size_t ws_size,
                              hipStream_t stream){
    (void)in_sizes; (void)n_in; (void)out_size; (void)ws_size;
    const float* dec_output = (const float*)d_in[0];
    const float* h          = (const float*)d_in[1];
    const float* c          = (const float*)d_in[2];
    const float* dec_inp    = (const float*)d_in[3];
    const float* enc_op     = (const float*)d_in[4];
    const float* enc_op1    = (const float*)d_in[5];
    const int*   src        = (const int*)d_in[6];
    const float* W_dec      = (const float*)d_in[7];
    const float* b_dec      = (const float*)d_in[8];
    const float* w_attn     = (const float*)d_in[9];
    const float* W_v1       = (const float*)d_in[10];
    const float* b_v1       = (const float*)d_in[11];
    const float* W_v2       = (const float*)d_in[12];
    const float* b_v2       = (const float*)d_in[13];
    const float* W_p        = (const float*)d_in[14];
    const float* b_p        = (const float*)d_in[15];
    const float* bn_g       = (const float*)d_in[16];
    const float* bn_b       = (const float*)d_in[17];
    const float* bn_m       = (const float*)d_in[18];
    const float* bn_v       = (const float*)d_in[19];

    float* ws       = (float*)d_ws;
    float* dec_op1  = ws;               // 32768
    float* attn_lg  = ws + 32768;       // 32768
    float* ctx_part = ws + 65536;       // 1048576
    float* hidden   = ws + 1114112;     // 16384
    float* pg       = ws + 1130496;     // 32
    float* logits   = ws + 1130528;     // 1568000  (total ws use ~10.8 MB)

    float* pf   = (float*)d_out;        // [32,50000]
    float* attn = pf + 1600000;         // [32,1024]
    float* ctx  = pf + 1632768;         // [32,1024]

    hipMemsetAsync(logits, 0, (size_t)B * VO * sizeof(float), stream);

    k1_decop1 <<<dim3(B, 4),   256, 0, stream>>>(h, c, W_dec, b_dec, dec_op1);
    k2a_logit <<<dim3(B, 256), 256, 0, stream>>>(enc_op1, dec_op1, w_attn, attn_lg);
    k2b_attnsm<<<B,            256, 0, stream>>>(attn_lg, src, attn);
    k2c_ctxpart<<<dim3(B, 32), 256, 0, stream>>>(enc_op, attn, ctx_part);
    k2d_ctxbn <<<B,            256, 0, stream>>>(ctx_part, bn_g, bn_b, bn_m, bn_v, ctx);
    k3_hidden <<<dim3(B, 2),   256, 0, stream>>>(dec_output, ctx, W_v1, b_v1, hidden);
    k3b_pgen  <<<B,            256, 0, stream>>>(ctx, h, c, dec_inp, W_p, b_p, pg);
    k4_logits <<<dim3(192, 2), 256, 0, stream>>>(W_v2, hidden, logits);
    k5a_vocab <<<B,            256, 0, stream>>>(logits, b_v2, pg, pf);
    k5b_scatter<<<B,           256, 0, stream>>>(src, attn, pg, pf);
    k5c_eps   <<<(B * V + 255) / 256, 256, 0, stream>>>(pf, B * V);
}

// Round 2
// 695.862 us; speedup vs baseline: 1.0030x; 1.0030x over previous
//
#include <hip/hip_runtime.h>

#define B   32
#define S   1024
#define D   512
#define D2  1024
#define D5  2560
#define V   50000
#define VO  49000

__device__ __forceinline__ float fast_tanh(float x){
    float e = __expf(2.0f * x);
    return 1.0f - __fdividef(2.0f, e + 1.0f);
}

// Skinny GEMM: C[b][v] += sum_{k in slice} W[v][k] * X[b][k]
// X(b,k) = (k < xsplit ? xa[b*xstra+k] : xb[b*xstrb+k-xsplit]) + (xbias?xbias[k]:0)
// Block: 512 v-rows x 32 b, K-slice KS (multiple of 16). W read ONCE total.
// LDS: W-tile transposed [16k][512v] (stride 516, 2-way-max write conflicts = free;
//      inner reads = contiguous-16B-per-lane pattern, conflict-free),
//      X-tile [16k][32b] (wave-uniform broadcast reads).
__global__ __launch_bounds__(256) void gemm_skinny(
    const float* __restrict__ W, int Nreal, int K,
    const float* __restrict__ xa, const float* __restrict__ xb,
    int xsplit, int xstra, int xstrb, const float* __restrict__ xbias,
    float* __restrict__ C, int KS)
{
    __shared__ float sW[16 * 516];
    __shared__ float sX[16 * 32];
    const int t    = threadIdx.x;
    const int v0   = blockIdx.x * 512;
    const int ks0  = blockIdx.y * KS;
    const int lane = t & 63;
    const int b0   = (t >> 6) * 8;

    float acc[8][8];
    #pragma unroll
    for (int i = 0; i < 8; ++i)
        #pragma unroll
        for (int j = 0; j < 8; ++j) acc[i][j] = 0.f;

    const int qq    = t & 3;       // k-quad for staging
    const int rbase = t >> 2;      // row base for W staging

    for (int k0 = ks0; k0 < ks0 + KS; k0 += 16){
        __syncthreads();
        // stage X: 16k x 32b
        if (t < 128){
            int b = t >> 2;
            int kk = k0 + qq * 4;
            #pragma unroll
            for (int e = 0; e < 4; ++e){
                int k = kk + e;
                float xv = (k < xsplit) ? xa[b * xstra + k] : xb[b * xstrb + (k - xsplit)];
                if (xbias) xv += xbias[k];
                sX[(qq * 4 + e) * 32 + b] = xv;
            }
        }
        // stage W transposed: 512 rows x 16 k
        #pragma unroll
        for (int p = 0; p < 8; ++p){
            int r = p * 64 + rbase;
            int v = v0 + r;
            float4 w = (v < Nreal) ? *(const float4*)&W[(size_t)v * K + k0 + qq * 4]
                                   : make_float4(0.f, 0.f, 0.f, 0.f);
            sW[(qq * 4 + 0) * 516 + r] = w.x;
            sW[(qq * 4 + 1) * 516 + r] = w.y;
            sW[(qq * 4 + 2) * 516 + r] = w.z;
            sW[(qq * 4 + 3) * 516 + r] = w.w;
        }
        __syncthreads();
        #pragma unroll
        for (int kk = 0; kk < 16; ++kk){
            const float4 w0 = *(const float4*)&sW[kk * 516 + lane * 4];
            const float4 w1 = *(const float4*)&sW[kk * 516 + 256 + lane * 4];
            const float4 x0 = *(const float4*)&sX[kk * 32 + b0];
            const float4 x1 = *(const float4*)&sX[kk * 32 + b0 + 4];
            const float wv[8] = {w0.x, w0.y, w0.z, w0.w, w1.x, w1.y, w1.z, w1.w};
            const float xv[8] = {x0.x, x0.y, x0.z, x0.w, x1.x, x1.y, x1.z, x1.w};
            #pragma unroll
            for (int i = 0; i < 8; ++i)
                #pragma unroll
                for (int j = 0; j < 8; ++j)
                    acc[i][j] += wv[i] * xv[j];
        }
    }
    #pragma unroll
    for (int i = 0; i < 8; ++i){
        int v = v0 + ((i < 4) ? (lane * 4 + i) : (256 + lane * 4 + (i - 4)));
        if (v < Nreal){
            #pragma unroll
            for (int j = 0; j < 8; ++j)
                atomicAdd(&C[(size_t)(b0 + j) * Nreal + v], acc[i][j]);
        }
    }
}

// K2a: attn logit[b][s] = sum_d tanh(enc1[b][s][d] + dec_op1[b][d] + b_dec[d]) * w_attn[d]
__global__ void k2a_logit(const float* __restrict__ enc1, const float* __restrict__ dop1,
                          const float* __restrict__ bdec, const float* __restrict__ wat,
                          float* __restrict__ lg){
    int b = blockIdx.x;
    int wave = threadIdx.x >> 6, lane = threadIdx.x & 63;
    int s = blockIdx.y * 4 + wave;
    __shared__ float sd[D2], sw[D2];
    for (int i = threadIdx.x; i < D2; i += 256){
        sd[i] = dop1[b * D2 + i] + bdec[i];
        sw[i] = wat[i];
    }
    __syncthreads();
    const float4* row = (const float4*)(enc1 + ((size_t)b * S + s) * D2);
    const float4* sd4 = (const float4*)sd;
    const float4* sw4 = (const float4*)sw;
    float acc = 0.f;
    #pragma unroll
    for (int i = 0; i < 4; ++i){
        int k4 = i * 64 + lane;
        float4 e = row[k4]; float4 dv = sd4[k4]; float4 wv = sw4[k4];
        acc += fast_tanh(e.x + dv.x) * wv.x + fast_tanh(e.y + dv.y) * wv.y
             + fast_tanh(e.z + dv.z) * wv.z + fast_tanh(e.w + dv.w) * wv.w;
    }
    #pragma unroll
    for (int off = 32; off > 0; off >>= 1) acc += __shfl_down(acc, off, 64);
    if (lane == 0) lg[b * S + s] = acc;
}

// K2b: masked softmax + renormalize -> attn (output 1)
__global__ void k2b_attnsm(const float* __restrict__ lg, const int* __restrict__ src,
                           float* __restrict__ attn){
    int b = blockIdx.x, t = threadIdx.x;
    __shared__ float red[256];
    float l[4];
    float m = -1e30f;
    #pragma unroll
    for (int i = 0; i < 4; ++i){ l[i] = lg[b * S + t + i * 256]; m = fmaxf(m, l[i]); }
    red[t] = m; __syncthreads();
    for (int o = 128; o > 0; o >>= 1){
        if (t < o) red[t] = fmaxf(red[t], red[t + o]);
        __syncthreads();
    }
    m = red[0]; __syncthreads();
    float e[4]; float sum = 0.f;
    #pragma unroll
    for (int i = 0; i < 4; ++i){
        int s = t + i * 256;
        bool keep = src[b * S + s] != 0;
        e[i] = keep ? __expf(l[i] - m) : 0.f;
        sum += e[i];
    }
    red[t] = sum; __syncthreads();
    for (int o = 128; o > 0; o >>= 1){
        if (t < o) red[t] += red[t + o];
        __syncthreads();
    }
    float inv = 1.0f / red[0];
    #pragma unroll
    for (int i = 0; i < 4; ++i) attn[b * S + t + i * 256] = e[i] * inv;
}

// K2c: context partials over s-splits
__global__ void k2c_ctxpart(const float* __restrict__ enc, const float* __restrict__ attn,
                            float* __restrict__ part){
    int b = blockIdx.x, sp = blockIdx.y, t = threadIdx.x;
    __shared__ float sa[32];
    if (t < 32) sa[t] = attn[b * S + sp * 32 + t];
    __syncthreads();
    const float4* base = (const float4*)(enc + ((size_t)b * S + sp * 32) * D2);
    float4 acc = make_float4(0.f, 0.f, 0.f, 0.f);
    #pragma unroll 4
    for (int s = 0; s < 32; ++s){
        float a = sa[s];
        float4 e = base[s * (D2 / 4) + t];
        acc.x += a * e.x; acc.y += a * e.y; acc.z += a * e.z; acc.w += a * e.w;
    }
    ((float4*)(part + ((size_t)(b * 32 + sp)) * D2))[t] = acc;
}

// K2d: reduce partials + batchnorm -> context (output 2)
__global__ void k2d_ctxbn(const float* __restrict__ part, const float* __restrict__ gamma,
                          const float* __restrict__ beta, const float* __restrict__ mean,
                          const float* __restrict__ var, float* __restrict__ ctx){
    int b = blockIdx.x, t = threadIdx.x;
    float4 acc = make_float4(0.f, 0.f, 0.f, 0.f);
    for (int sp = 0; sp < 32; ++sp){
        float4 p = ((const float4*)(part + ((size_t)(b * 32 + sp)) * D2))[t];
        acc.x += p.x; acc.y += p.y; acc.z += p.z; acc.w += p.w;
    }
    float4 g  = ((const float4*)gamma)[t];
    float4 be = ((const float4*)beta)[t];
    float4 mn = ((const float4*)mean)[t];
    float4 vr = ((const float4*)var)[t];
    acc.x = (acc.x - mn.x) * rsqrtf(vr.x + 1e-5f) * g.x + be.x;
    acc.y = (acc.y - mn.y) * rsqrtf(vr.y + 1e-5f) * g.y + be.y;
    acc.z = (acc.z - mn.z) * rsqrtf(vr.z + 1e-5f) * g.z + be.z;
    acc.w = (acc.w - mn.w) * rsqrtf(vr.w + 1e-5f) * g.w + be.w;
    ((float4*)(ctx + (size_t)b * D2))[t] = acc;
}

// K3b: p_gen[b] = sigmoid([ctx;h;c;dec_inp] . W_p + b_p)
__global__ void k3b_pgen(const float* __restrict__ ctx, const float* __restrict__ h,
                         const float* __restrict__ c, const float* __restrict__ di,
                         const float* __restrict__ Wp, const float* __restrict__ bp,
                         float* __restrict__ pg){
    int b = blockIdx.x, t = threadIdx.x;
    float acc = 0.f;
    for (int k = t; k < D5; k += 256){
        float x;
        if (k < D2)            x = ctx[b * D2 + k];
        else if (k < D2 + D)   x = h[b * D + (k - D2)];
        else if (k < 2 * D2)   x = c[b * D + (k - D2 - D)];
        else                   x = di[b * D + (k - 2 * D2)];
        acc += x * Wp[k];
    }
    __shared__ float red[256];
    red[t] = acc; __syncthreads();
    for (int o = 128; o > 0; o >>= 1){
        if (t < o) red[t] += red[t + o];
        __syncthreads();
    }
    if (t == 0){
        float z = red[0] + bp[0];
        pg[b] = 1.0f / (1.0f + __expf(-z));
    }
}

// K5a: per-b online softmax over logits -> p_final = p_gen * p_vocab, pad zeros
__global__ void k5a_vocab(const float* __restrict__ lg, const float* __restrict__ b2,
                          const float* __restrict__ pg, float* __restrict__ pf){
    int b = blockIdx.x, t = threadIdx.x;
    float m = -1e30f, sum = 0.f;
    for (int v = t; v < VO; v += 256){
        float l = lg[(size_t)b * VO + v] + b2[v];
        float nm = fmaxf(m, l);
        sum = sum * __expf(m - nm) + __expf(l - nm);
        m = nm;
    }
    __shared__ float sm[256], ss[256];
    sm[t] = m; ss[t] = sum; __syncthreads();
    for (int o = 128; o > 0; o >>= 1){
        if (t < o){
            float m1 = sm[t], m2 = sm[t + o];
            float M = fmaxf(m1, m2);
            ss[t] = ss[t] * __expf(m1 - M) + ss[t + o] * __expf(m2 - M);
            sm[t] = M;
        }
        __syncthreads();
    }
    float M = sm[0];
    float scale = pg[b] / ss[0];
    for (int v = t; v < VO; v += 256){
        float l = lg[(size_t)b * VO + v] + b2[v];
        pf[(size_t)b * V + v] = scale * __expf(l - M);
    }
    for (int v = VO + t; v < V; v += 256) pf[(size_t)b * V + v] = 0.f;
}

// K5b: scatter add (1-p_gen)*attn at src indices
__global__ void k5b_scatter(const int* __restrict__ src, const float* __restrict__ attn,
                            const float* __restrict__ pg, float* __restrict__ pf){
    int b = blockIdx.x, t = threadIdx.x;
    float c1 = 1.0f - pg[b];
    for (int s = t; s < S; s += 256){
        int idx = src[b * S + s];
        atomicAdd(&pf[(size_t)b * V + idx], c1 * attn[b * S + s]);
    }
}

// K5c: p_final += (p_final == 0) * 1e-12
__global__ void k5c_eps(float* __restrict__ pf, int n){
    int i = blockIdx.x * 256 + threadIdx.x;
    if (i < n && pf[i] == 0.0f) pf[i] = 1e-12f;
}

extern "C" void kernel_launch(void* const* d_in, const int* in_sizes, int n_in,
                              void* d_out, int out_size, void* d_ws, size_t ws_size,
                              hipStream_t stream){
    (void)in_sizes; (void)n_in; (void)out_size; (void)ws_size;
    const float* dec_output = (const float*)d_in[0];
    const float* h          = (const float*)d_in[1];
    const float* c          = (const float*)d_in[2];
    const float* dec_inp    = (const float*)d_in[3];
    const float* enc_op     = (const float*)d_in[4];
    const float* enc_op1    = (const float*)d_in[5];
    const int*   src        = (const int*)d_in[6];
    const float* W_dec      = (const float*)d_in[7];
    const float* b_dec      = (const float*)d_in[8];
    const float* w_attn     = (const float*)d_in[9];
    const float* W_v1       = (const float*)d_in[10];
    const float* b_v1       = (const float*)d_in[11];
    const float* W_v2       = (const float*)d_in[12];
    const float* b_v2       = (const float*)d_in[13];
    const float* W_p        = (const float*)d_in[14];
    const float* b_p        = (const float*)d_in[15];
    const float* bn_g       = (const float*)d_in[16];
    const float* bn_b       = (const float*)d_in[17];
    const float* bn_m       = (const float*)d_in[18];
    const float* bn_v       = (const float*)d_in[19];

    float* ws       = (float*)d_ws;
    // zeroed region (contiguous): dec_op1, hidden, logits
    float* dec_op1  = ws;                 // 32768
    float* hidden   = ws + 32768;         // 16384
    float* logits   = ws + 49152;         // 1568000
    // non-zeroed scratch
    float* attn_lg  = ws + 1617152;       // 32768
    float* ctx_part = ws + 1649920;       // 1048576
    float* pg       = ws + 2698496;       // 32

    float* pf   = (float*)d_out;          // [32,50000]
    float* attn = pf + 1600000;           // [32,1024]
    float* ctx  = pf + 1632768;           // [32,1024]

    hipMemsetAsync(ws, 0, (size_t)(49152 + 1568000) * sizeof(float), stream);

    // k1: dec_op1[b][j] += [h;c][b] . W_dec[j]  (bias folded into k2a)
    gemm_skinny<<<dim3(2, 64), 256, 0, stream>>>(W_dec, D2, D2, h, c, D, D, D,
                                                 nullptr, dec_op1, 16);
    k2a_logit <<<dim3(B, 256), 256, 0, stream>>>(enc_op1, dec_op1, b_dec, w_attn, attn_lg);
    k2b_attnsm<<<B,            256, 0, stream>>>(attn_lg, src, attn);
    k2c_ctxpart<<<dim3(B, 32), 256, 0, stream>>>(enc_op, attn, ctx_part);
    k2d_ctxbn <<<B,            256, 0, stream>>>(ctx_part, bn_g, bn_b, bn_m, bn_v, ctx);
    // k3: hidden[b][j] += [dec_output;ctx][b] . W_v1[j]  (b_v1 folded into k4 staging)
    gemm_skinny<<<dim3(1, 96), 256, 0, stream>>>(W_v1, D, D + D2, dec_output, ctx,
                                                 D, D, D2, nullptr, hidden, 16);
    k3b_pgen  <<<B,            256, 0, stream>>>(ctx, h, c, dec_inp, W_p, b_p, pg);
    // k4: logits[b][v] += (hidden[b]+b_v1) . W_v2[v]  (b_v2 folded into k5a)
    gemm_skinny<<<dim3(96, 4), 256, 0, stream>>>(W_v2, VO, D, hidden, hidden,
                                                 D, D, D, b_v1, logits, 128);
    k5a_vocab <<<B,            256, 0, stream>>>(logits, b_v2, pg, pf);
    k5b_scatter<<<B,           256, 0, stream>>>(src, attn, pg, pf);
    k5c_eps   <<<(B * V + 255) / 256, 256, 0, stream>>>(pf, B * V);
}

// Round 3
// 501.193 us; speedup vs baseline: 1.3926x; 1.3884x over previous
//
#include <hip/hip_runtime.h>

#define B   32
#define S   1024
#define D   512
#define D2  1024
#define D5  2560
#define V   50000
#define VO  49000
#define NCH 14          // vocab chunks for softmax finalize (14*3500 = 49000)
#define CHW 3500

__device__ __forceinline__ float fast_tanh(float x){
    float e = __expf(2.0f * x);
    return 1.0f - __fdividef(2.0f, e + 1.0f);
}

// gemm_nt: parts[(ks*B + b)*Nreal + v] = sum_{k in slice ks} W[v][k] * X(b,k)
// X(b,k) = (k < xsplit ? xa[b*xstra+k] : xb[b*xstrb+k-xsplit]) + (xbias?xbias[k]:0)
// v-tile 256 (thread t stages row v0+t), 32 b, 16-k inner tiles, register-prefetch
// pipeline (next tile's global loads issued between barriers, overlap with FMA).
// NO atomics: each block exclusively owns (v-tile, k-slice) -> plain stores.
__global__ __launch_bounds__(256) void gemm_nt(
    const float* __restrict__ W, int Nreal, int K,
    const float* __restrict__ xa, const float* __restrict__ xb,
    int xsplit, int xstra, int xstrb, const float* __restrict__ xbias,
    float* __restrict__ parts, int KS)
{
    __shared__ float sW[16 * 260];   // [k][v] transposed, stride 260 (2-way max = free)
    __shared__ float sX[16 * 32];    // [k][b]
    const int t    = threadIdx.x;
    const int lane = t & 63;
    const int v0   = blockIdx.x * 256;
    const int ks0  = blockIdx.y * KS;
    const int b0   = (t >> 6) * 8;

    const int vrow  = v0 + t;
    const size_t wb = (size_t)((vrow < Nreal) ? vrow : (Nreal - 1)) * K;

    float acc[4][8];
    #pragma unroll
    for (int i = 0; i < 4; ++i)
        #pragma unroll
        for (int j = 0; j < 8; ++j) acc[i][j] = 0.f;

    const int  xbi  = t >> 2;        // b for X staging
    const int  xq   = t & 3;         // k-quad for X staging
    const bool xact = t < 128;

    float4 wreg[4];
    float  xreg[4];
    // prefetch tile 0
    #pragma unroll
    for (int e = 0; e < 4; ++e) wreg[e] = *(const float4*)&W[wb + ks0 + e * 4];
    if (xact){
        #pragma unroll
        for (int e = 0; e < 4; ++e){
            int k = ks0 + xq * 4 + e;
            float xv = (k < xsplit) ? xa[xbi * xstra + k] : xb[xbi * xstrb + (k - xsplit)];
            if (xbias) xv += xbias[k];
            xreg[e] = xv;
        }
    }

    const int ntiles = KS >> 4;
    for (int tl = 0; tl < ntiles; ++tl){
        // staged regs -> LDS
        #pragma unroll
        for (int e = 0; e < 4; ++e){
            sW[(e * 4 + 0) * 260 + t] = wreg[e].x;
            sW[(e * 4 + 1) * 260 + t] = wreg[e].y;
            sW[(e * 4 + 2) * 260 + t] = wreg[e].z;
            sW[(e * 4 + 3) * 260 + t] = wreg[e].w;
        }
        if (xact){
            #pragma unroll
            for (int e = 0; e < 4; ++e) sX[(xq * 4 + e) * 32 + xbi] = xreg[e];
        }
        __syncthreads();
        // prefetch next tile (loads stay in flight across the FMA block below)
        if (tl + 1 < ntiles){
            int kn = ks0 + (tl + 1) * 16;
            #pragma unroll
            for (int e = 0; e < 4; ++e) wreg[e] = *(const float4*)&W[wb + kn + e * 4];
            if (xact){
                #pragma unroll
                for (int e = 0; e < 4; ++e){
                    int k = kn + xq * 4 + e;
                    float xv = (k < xsplit) ? xa[xbi * xstra + k] : xb[xbi * xstrb + (k - xsplit)];
                    if (xbias) xv += xbias[k];
                    xreg[e] = xv;
                }
            }
        }
        // compute 16 k-steps from LDS
        #pragma unroll
        for (int kk = 0; kk < 16; ++kk){
            const float4 w0 = *(const float4*)&sW[kk * 260 + lane * 4];
            const float4 x0 = *(const float4*)&sX[kk * 32 + b0];
            const float4 x1 = *(const float4*)&sX[kk * 32 + b0 + 4];
            const float wv[4] = {w0.x, w0.y, w0.z, w0.w};
            const float xv[8] = {x0.x, x0.y, x0.z, x0.w, x1.x, x1.y, x1.z, x1.w};
            #pragma unroll
            for (int i = 0; i < 4; ++i)
                #pragma unroll
                for (int j = 0; j < 8; ++j)
                    acc[i][j] += wv[i] * xv[j];
        }
        __syncthreads();
    }
    // epilogue: exclusive plain stores
    const int vbase = v0 + lane * 4;
    if (vbase < Nreal){
        const size_t pb = (size_t)blockIdx.y * B;
        #pragma unroll
        for (int j = 0; j < 8; ++j){
            float4 o = make_float4(acc[0][j], acc[1][j], acc[2][j], acc[3][j]);
            *(float4*)&parts[(pb + b0 + j) * (size_t)Nreal + vbase] = o;
        }
    }
}

// reduce parts over splits: out[i] = sum_p parts[p*n + i], i in [0, n)
__global__ void kreduce(const float* __restrict__ parts, float* __restrict__ out,
                        int n, int nsplit){
    int i = blockIdx.x * 256 + threadIdx.x;
    if (i < n){
        float s = 0.f;
        for (int p = 0; p < nsplit; ++p) s += parts[(size_t)p * n + i];
        out[i] = s;
    }
}

// K2a: attn logit[b][s] = sum_d tanh(enc1[b][s][d] + dec_op1[b][d] + b_dec[d]) * w_attn[d]
// 16 s-rows per block (4 per wave) to amortize staging.
__global__ void k2a_logit(const float* __restrict__ enc1, const float* __restrict__ dop1,
                          const float* __restrict__ bdec, const float* __restrict__ wat,
                          float* __restrict__ lg){
    int b = blockIdx.x;
    int wave = threadIdx.x >> 6, lane = threadIdx.x & 63;
    int s0 = blockIdx.y * 16 + wave * 4;
    __shared__ float sd[D2], sw[D2];
    for (int i = threadIdx.x; i < D2; i += 256){
        sd[i] = dop1[b * D2 + i] + bdec[i];
        sw[i] = wat[i];
    }
    __syncthreads();
    const float4* sd4 = (const float4*)sd;
    const float4* sw4 = (const float4*)sw;
    for (int r = 0; r < 4; ++r){
        int s = s0 + r;
        const float4* row = (const float4*)(enc1 + ((size_t)b * S + s) * D2);
        float acc = 0.f;
        #pragma unroll
        for (int i = 0; i < 4; ++i){
            int k4 = i * 64 + lane;
            float4 e = row[k4]; float4 dv = sd4[k4]; float4 wv = sw4[k4];
            acc += fast_tanh(e.x + dv.x) * wv.x + fast_tanh(e.y + dv.y) * wv.y
                 + fast_tanh(e.z + dv.z) * wv.z + fast_tanh(e.w + dv.w) * wv.w;
        }
        #pragma unroll
        for (int off = 32; off > 0; off >>= 1) acc += __shfl_down(acc, off, 64);
        if (lane == 0) lg[b * S + s] = acc;
    }
}

// K2b: masked softmax + renormalize -> attn (output 1)
__global__ void k2b_attnsm(const float* __restrict__ lg, const int* __restrict__ src,
                           float* __restrict__ attn){
    int b = blockIdx.x, t = threadIdx.x;
    __shared__ float red[256];
    float l[4];
    float m = -1e30f;
    #pragma unroll
    for (int i = 0; i < 4; ++i){ l[i] = lg[b * S + t + i * 256]; m = fmaxf(m, l[i]); }
    red[t] = m; __syncthreads();
    for (int o = 128; o > 0; o >>= 1){
        if (t < o) red[t] = fmaxf(red[t], red[t + o]);
        __syncthreads();
    }
    m = red[0]; __syncthreads();
    float e[4]; float sum = 0.f;
    #pragma unroll
    for (int i = 0; i < 4; ++i){
        int s = t + i * 256;
        bool keep = src[b * S + s] != 0;
        e[i] = keep ? __expf(l[i] - m) : 0.f;
        sum += e[i];
    }
    red[t] = sum; __syncthreads();
    for (int o = 128; o > 0; o >>= 1){
        if (t < o) red[t] += red[t + o];
        __syncthreads();
    }
    float inv = 1.0f / red[0];
    #pragma unroll
    for (int i = 0; i < 4; ++i) attn[b * S + t + i * 256] = e[i] * inv;
}

// K2c: context partials over s-splits
__global__ void k2c_ctxpart(const float* __restrict__ enc, const float* __restrict__ attn,
                            float* __restrict__ part){
    int b = blockIdx.x, sp = blockIdx.y, t = threadIdx.x;
    __shared__ float sa[32];
    if (t < 32) sa[t] = attn[b * S + sp * 32 + t];
    __syncthreads();
    const float4* base = (const float4*)(enc + ((size_t)b * S + sp * 32) * D2);
    float4 acc = make_float4(0.f, 0.f, 0.f, 0.f);
    #pragma unroll 4
    for (int s = 0; s < 32; ++s){
        float a = sa[s];
        float4 e = base[s * (D2 / 4) + t];
        acc.x += a * e.x; acc.y += a * e.y; acc.z += a * e.z; acc.w += a * e.w;
    }
    ((float4*)(part + ((size_t)(b * 32 + sp)) * D2))[t] = acc;
}

// K2d: reduce partials + batchnorm -> context (output 2)
__global__ void k2d_ctxbn(const float* __restrict__ part, const float* __restrict__ gamma,
                          const float* __restrict__ beta, const float* __restrict__ mean,
                          const float* __restrict__ var, float* __restrict__ ctx){
    int b = blockIdx.x, t = threadIdx.x;
    float4 acc = make_float4(0.f, 0.f, 0.f, 0.f);
    for (int sp = 0; sp < 32; ++sp){
        float4 p = ((const float4*)(part + ((size_t)(b * 32 + sp)) * D2))[t];
        acc.x += p.x; acc.y += p.y; acc.z += p.z; acc.w += p.w;
    }
    float4 g  = ((const float4*)gamma)[t];
    float4 be = ((const float4*)beta)[t];
    float4 mn = ((const float4*)mean)[t];
    float4 vr = ((const float4*)var)[t];
    acc.x = (acc.x - mn.x) * rsqrtf(vr.x + 1e-5f) * g.x + be.x;
    acc.y = (acc.y - mn.y) * rsqrtf(vr.y + 1e-5f) * g.y + be.y;
    acc.z = (acc.z - mn.z) * rsqrtf(vr.z + 1e-5f) * g.z + be.z;
    acc.w = (acc.w - mn.w) * rsqrtf(vr.w + 1e-5f) * g.w + be.w;
    ((float4*)(ctx + (size_t)b * D2))[t] = acc;
}

// K3b: p_gen[b] = sigmoid([ctx;h;c;dec_inp] . W_p + b_p)
__global__ void k3b_pgen(const float* __restrict__ ctx, const float* __restrict__ h,
                         const float* __restrict__ c, const float* __restrict__ di,
                         const float* __restrict__ Wp, const float* __restrict__ bp,
                         float* __restrict__ pg){
    int b = blockIdx.x, t = threadIdx.x;
    float acc = 0.f;
    for (int k = t; k < D5; k += 256){
        float x;
        if (k < D2)            x = ctx[b * D2 + k];
        else if (k < D2 + D)   x = h[b * D + (k - D2)];
        else if (k < 2 * D2)   x = c[b * D + (k - D2 - D)];
        else                   x = di[b * D + (k - 2 * D2)];
        acc += x * Wp[k];
    }
    __shared__ float red[256];
    red[t] = acc; __syncthreads();
    for (int o = 128; o > 0; o >>= 1){
        if (t < o) red[t] += red[t + o];
        __syncthreads();
    }
    if (t == 0){
        float z = red[0] + bp[0];
        pg[b] = 1.0f / (1.0f + __expf(-z));
    }
}

// kA: per (b, chunk): reduce 4 logit parts + b_v2 -> lred; chunk max/sumexp stats
__global__ void kA_stats(const float* __restrict__ p4, const float* __restrict__ b2,
                         float* __restrict__ lred, float* __restrict__ mch,
                         float* __restrict__ sch){
    int b = blockIdx.x, c = blockIdx.y, t = threadIdx.x;
    const size_t PS = (size_t)B * VO;
    float m = -1e30f, s = 0.f;
    for (int v = c * CHW + t; v < (c + 1) * CHW; v += 256){
        size_t idx = (size_t)b * VO + v;
        float l = p4[idx] + p4[PS + idx] + p4[2 * PS + idx] + p4[3 * PS + idx] + b2[v];
        lred[idx] = l;
        float nm = fmaxf(m, l);
        s = s * __expf(m - nm) + __expf(l - nm);
        m = nm;
    }
    __shared__ float sm[256], ss[256];
    sm[t] = m; ss[t] = s; __syncthreads();
    for (int o = 128; o > 0; o >>= 1){
        if (t < o){
            float m1 = sm[t], m2 = sm[t + o];
            float M = fmaxf(m1, m2);
            ss[t] = ss[t] * __expf(m1 - M) + ss[t + o] * __expf(m2 - M);
            sm[t] = M;
        }
        __syncthreads();
    }
    if (t == 0){ mch[b * NCH + c] = sm[0]; sch[b * NCH + c] = ss[0]; }
}

// kB: combine chunk stats -> M[b], scale[b] = pg[b]/S[b]
__global__ void kB_comb(const float* __restrict__ mch, const float* __restrict__ sch,
                        const float* __restrict__ pg, float* __restrict__ Mb,
                        float* __restrict__ scaleb){
    int b = threadIdx.x;
    if (b < B){
        float M = -1e30f;
        for (int c = 0; c < NCH; ++c) M = fmaxf(M, mch[b * NCH + c]);
        float Ssum = 0.f;
        for (int c = 0; c < NCH; ++c) Ssum += sch[b * NCH + c] * __expf(mch[b * NCH + c] - M);
        Mb[b] = M;
        scaleb[b] = pg[b] / Ssum;
    }
}

// kC: pf[b][v] = scale[b] * exp(lred - M[b]); chunk NCH fills the OOV pad with 0
__global__ void kC_final(const float* __restrict__ lred, const float* __restrict__ Mb,
                         const float* __restrict__ scaleb, float* __restrict__ pf){
    int b = blockIdx.x, c = blockIdx.y, t = threadIdx.x;
    if (c == NCH){
        for (int v = VO + t; v < V; v += 256) pf[(size_t)b * V + v] = 0.f;
        return;
    }
    float M = Mb[b], sc = scaleb[b];
    for (int v = c * CHW + t; v < (c + 1) * CHW; v += 256)
        pf[(size_t)b * V + v] = sc * __expf(lred[(size_t)b * VO + v] - M);
}

// K5b: scatter add (1-p_gen)*attn at src indices (32K atomics — negligible)
__global__ void k5b_scatter(const int* __restrict__ src, const float* __restrict__ attn,
                            const float* __restrict__ pg, float* __restrict__ pf){
    int b = blockIdx.x, t = threadIdx.x;
    float c1 = 1.0f - pg[b];
    for (int s = t; s < S; s += 256){
        int idx = src[b * S + s];
        atomicAdd(&pf[(size_t)b * V + idx], c1 * attn[b * S + s]);
    }
}

// K5c: p_final += (p_final == 0) * 1e-12
__global__ void k5c_eps(float* __restrict__ pf, int n){
    int i = blockIdx.x * 256 + threadIdx.x;
    if (i < n && pf[i] == 0.0f) pf[i] = 1e-12f;
}

extern "C" void kernel_launch(void* const* d_in, const int* in_sizes, int n_in,
                              void* d_out, int out_size, void* d_ws, size_t ws_size,
                              hipStream_t stream){
    (void)in_sizes; (void)n_in; (void)out_size; (void)ws_size;
    const float* dec_output = (const float*)d_in[0];
    const float* h          = (const float*)d_in[1];
    const float* c          = (const float*)d_in[2];
    const float* dec_inp    = (const float*)d_in[3];
    const float* enc_op     = (const float*)d_in[4];
    const float* enc_op1    = (const float*)d_in[5];
    const int*   src        = (const int*)d_in[6];
    const float* W_dec      = (const float*)d_in[7];
    const float* b_dec      = (const float*)d_in[8];
    const float* w_attn     = (const float*)d_in[9];
    const float* W_v1       = (const float*)d_in[10];
    const float* b_v1       = (const float*)d_in[11];
    const float* W_v2       = (const float*)d_in[12];
    const float* b_v2       = (const float*)d_in[13];
    const float* W_p        = (const float*)d_in[14];
    const float* b_p        = (const float*)d_in[15];
    const float* bn_g       = (const float*)d_in[16];
    const float* bn_b       = (const float*)d_in[17];
    const float* bn_m       = (const float*)d_in[18];
    const float* bn_v       = (const float*)d_in[19];

    float* ws = (float*)d_ws;
    float* p1       = ws;                    // 16*32768   = 524288
    float* dec_op1  = ws + 524288;           // 32768
    float* p3       = ws + 557056;           // 16*16384   = 262144
    float* hidden   = ws + 819200;           // 16384
    float* p4       = ws + 835584;           // 4*1568000  = 6272000
    float* lred     = ws + 7107584;          // 1568000
    float* attn_lg  = ws + 8675584;          // 32768
    float* ctx_part = ws + 8708352;          // 1048576
    float* pg       = ws + 9756928;          // 32
    float* mch      = ws + 9756960;          // 448
    float* sch      = ws + 9757408;          // 448
    float* Mb       = ws + 9757856;          // 32
    float* scaleb   = ws + 9757888;          // 32  (total ~39 MB)

    float* pf   = (float*)d_out;             // [32,50000]
    float* attn = pf + 1600000;              // [32,1024]
    float* ctx  = pf + 1632768;              // [32,1024]

    // k1: dec_op1 = [h;c] @ W_dec^T  (16 k-splits, no atomics)
    gemm_nt <<<dim3(4, 16),  256, 0, stream>>>(W_dec, D2, D2, h, c, D, D, D,
                                               nullptr, p1, 64);
    kreduce <<<128,          256, 0, stream>>>(p1, dec_op1, B * D2, 16);
    k2a_logit<<<dim3(B, 64), 256, 0, stream>>>(enc_op1, dec_op1, b_dec, w_attn, attn_lg);
    k2b_attnsm<<<B,          256, 0, stream>>>(attn_lg, src, attn);
    k2c_ctxpart<<<dim3(B, 32), 256, 0, stream>>>(enc_op, attn, ctx_part);
    k2d_ctxbn<<<B,           256, 0, stream>>>(ctx_part, bn_g, bn_b, bn_m, bn_v, ctx);
    // k3: hidden = [dec_output;ctx] @ W_v1^T (b_v1 folded into k4 staging)
    gemm_nt <<<dim3(2, 16),  256, 0, stream>>>(W_v1, D, D + D2, dec_output, ctx,
                                               D, D, D2, nullptr, p3, 96);
    kreduce <<<64,           256, 0, stream>>>(p3, hidden, B * D, 16);
    k3b_pgen<<<B,            256, 0, stream>>>(ctx, h, c, dec_inp, W_p, b_p, pg);
    // k4: logit parts = (hidden + b_v1) @ W_v2^T  (4 k-splits, no atomics)
    gemm_nt <<<dim3(192, 4), 256, 0, stream>>>(W_v2, VO, D, hidden, hidden,
                                               D, D, D, b_v1, p4, 128);
    kA_stats<<<dim3(B, NCH), 256, 0, stream>>>(p4, b_v2, lred, mch, sch);
    kB_comb <<<1,             64, 0, stream>>>(mch, sch, pg, Mb, scaleb);
    kC_final<<<dim3(B, NCH + 1), 256, 0, stream>>>(lred, Mb, scaleb, pf);
    k5b_scatter<<<B,         256, 0, stream>>>(src, attn, pg, pf);
    k5c_eps <<<(B * V + 255) / 256, 256, 0, stream>>>(pf, B * V);
}

// Round 4
// 486.307 us; speedup vs baseline: 1.4352x; 1.0306x over previous
//
#include <hip/hip_runtime.h>

#define B    32
#define S    1024
#define D    512
#define D2   1024
#define D5   2560
#define V    50000
#define VO   49000
#define NCH  14          // vocab chunks for kC finalize (14*3500 = 49000)
#define CHW  3500
#define NCHV 383         // gemm_vocab v-tiles (383*128 = 49024 >= 49000)

__device__ __forceinline__ float fast_tanh(float x){
    float e = __expf(2.0f * x);
    return 1.0f - __fdividef(2.0f, e + 1.0f);
}

// gemm_nt: parts[(ks*B + b)*Nreal + v] = sum_{k in slice ks} W[v][k] * X(b,k)
// X(b,k) = (k < xsplit ? xa[b*xstra+k] : xb[b*xstrb+k-xsplit])
// v-tile 256, 32 b, 16-k inner tiles, register-prefetch pipeline. No atomics.
__global__ __launch_bounds__(256) void gemm_nt(
    const float* __restrict__ W, int Nreal, int K,
    const float* __restrict__ xa, const float* __restrict__ xb,
    int xsplit, int xstra, int xstrb,
    float* __restrict__ parts, int KS)
{
    __shared__ float sW[16 * 260];
    __shared__ float sX[16 * 32];
    const int t    = threadIdx.x;
    const int lane = t & 63;
    const int v0   = blockIdx.x * 256;
    const int ks0  = blockIdx.y * KS;
    const int b0   = (t >> 6) * 8;

    const int vrow  = v0 + t;
    const size_t wb = (size_t)((vrow < Nreal) ? vrow : (Nreal - 1)) * K;

    float acc[4][8];
    #pragma unroll
    for (int i = 0; i < 4; ++i)
        #pragma unroll
        for (int j = 0; j < 8; ++j) acc[i][j] = 0.f;

    const int  xbi  = t >> 2;
    const int  xq   = t & 3;
    const bool xact = t < 128;

    float4 wreg[4];
    float  xreg[4];
    #pragma unroll
    for (int e = 0; e < 4; ++e) wreg[e] = *(const float4*)&W[wb + ks0 + e * 4];
    if (xact){
        #pragma unroll
        for (int e = 0; e < 4; ++e){
            int k = ks0 + xq * 4 + e;
            xreg[e] = (k < xsplit) ? xa[xbi * xstra + k] : xb[xbi * xstrb + (k - xsplit)];
        }
    }

    const int ntiles = KS >> 4;
    for (int tl = 0; tl < ntiles; ++tl){
        #pragma unroll
        for (int e = 0; e < 4; ++e){
            sW[(e * 4 + 0) * 260 + t] = wreg[e].x;
            sW[(e * 4 + 1) * 260 + t] = wreg[e].y;
            sW[(e * 4 + 2) * 260 + t] = wreg[e].z;
            sW[(e * 4 + 3) * 260 + t] = wreg[e].w;
        }
        if (xact){
            #pragma unroll
            for (int e = 0; e < 4; ++e) sX[(xq * 4 + e) * 32 + xbi] = xreg[e];
        }
        __syncthreads();
        if (tl + 1 < ntiles){
            int kn = ks0 + (tl + 1) * 16;
            #pragma unroll
            for (int e = 0; e < 4; ++e) wreg[e] = *(const float4*)&W[wb + kn + e * 4];
            if (xact){
                #pragma unroll
                for (int e = 0; e < 4; ++e){
                    int k = kn + xq * 4 + e;
                    xreg[e] = (k < xsplit) ? xa[xbi * xstra + k] : xb[xbi * xstrb + (k - xsplit)];
                }
            }
        }
        #pragma unroll
        for (int kk = 0; kk < 16; ++kk){
            const float4 w0 = *(const float4*)&sW[kk * 260 + lane * 4];
            const float4 x0 = *(const float4*)&sX[kk * 32 + b0];
            const float4 x1 = *(const float4*)&sX[kk * 32 + b0 + 4];
            const float wv[4] = {w0.x, w0.y, w0.z, w0.w};
            const float xv[8] = {x0.x, x0.y, x0.z, x0.w, x1.x, x1.y, x1.z, x1.w};
            #pragma unroll
            for (int i = 0; i < 4; ++i)
                #pragma unroll
                for (int j = 0; j < 8; ++j)
                    acc[i][j] += wv[i] * xv[j];
        }
        __syncthreads();
    }
    const int vbase = v0 + lane * 4;
    if (vbase < Nreal){
        const size_t pb = (size_t)blockIdx.y * B;
        #pragma unroll
        for (int j = 0; j < 8; ++j){
            float4 o = make_float4(acc[0][j], acc[1][j], acc[2][j], acc[3][j]);
            *(float4*)&parts[(pb + b0 + j) * (size_t)Nreal + vbase] = o;
        }
    }
}

// reduce parts over splits (+ optional per-row bias, row length = bmask+1 pow2)
__global__ void kreduce(const float* __restrict__ parts, float* __restrict__ out,
                        int n, int nsplit, const float* __restrict__ bias, int bmask){
    int i = blockIdx.x * 256 + threadIdx.x;
    if (i < n){
        float s = 0.f;
        for (int p = 0; p < nsplit; ++p) s += parts[(size_t)p * n + i];
        if (bias) s += bias[i & bmask];
        out[i] = s;
    }
}

// gemm_vocab: lred[b][v] = (hidden[b]+) . W_v2[v] + b_v2[v]; fused per-v-tile
// online-softmax stats (mch/sch [B][NCHV]). v-tile 128, full K=512, no split.
__global__ __launch_bounds__(256) void gemm_vocab(
    const float* __restrict__ W, const float* __restrict__ hid,
    const float* __restrict__ b2, float* __restrict__ lred,
    float* __restrict__ mch, float* __restrict__ sch)
{
    __shared__ float sW[16 * 132];
    __shared__ float sX[16 * 32];
    const int t    = threadIdx.x;
    const int lane = t & 63;
    const int v0   = blockIdx.x * 128;
    const int b0   = (t >> 6) * 8;

    const int sr   = t & 127;          // staged W row within tile
    const int sh   = (t >> 7) * 8;     // k-half: 0 or 8
    const int vrow = v0 + sr;
    const size_t wb = (size_t)((vrow < VO) ? vrow : (VO - 1)) * D + sh;

    const int  xbi  = t >> 2;
    const int  xq   = (t & 3) * 4;
    const bool xact = t < 128;

    float acc[2][8];
    #pragma unroll
    for (int i = 0; i < 2; ++i)
        #pragma unroll
        for (int j = 0; j < 8; ++j) acc[i][j] = 0.f;

    float4 wreg[2];
    float  xreg[4];
    wreg[0] = *(const float4*)&W[wb];
    wreg[1] = *(const float4*)&W[wb + 4];
    if (xact){
        #pragma unroll
        for (int e = 0; e < 4; ++e) xreg[e] = hid[xbi * D + xq + e];
    }

    for (int tl = 0; tl < 32; ++tl){
        sW[(sh + 0) * 132 + sr] = wreg[0].x;
        sW[(sh + 1) * 132 + sr] = wreg[0].y;
        sW[(sh + 2) * 132 + sr] = wreg[0].z;
        sW[(sh + 3) * 132 + sr] = wreg[0].w;
        sW[(sh + 4) * 132 + sr] = wreg[1].x;
        sW[(sh + 5) * 132 + sr] = wreg[1].y;
        sW[(sh + 6) * 132 + sr] = wreg[1].z;
        sW[(sh + 7) * 132 + sr] = wreg[1].w;
        if (xact){
            #pragma unroll
            for (int e = 0; e < 4; ++e) sX[(xq + e) * 32 + xbi] = xreg[e];
        }
        __syncthreads();
        if (tl + 1 < 32){
            const int kn = (tl + 1) * 16;
            wreg[0] = *(const float4*)&W[wb + kn];
            wreg[1] = *(const float4*)&W[wb + kn + 4];
            if (xact){
                #pragma unroll
                for (int e = 0; e < 4; ++e) xreg[e] = hid[xbi * D + kn + xq + e];
            }
        }
        #pragma unroll
        for (int kk = 0; kk < 16; ++kk){
            const float2 w  = *(const float2*)&sW[kk * 132 + lane * 2];
            const float4 x0 = *(const float4*)&sX[kk * 32 + b0];
            const float4 x1 = *(const float4*)&sX[kk * 32 + b0 + 4];
            const float xv[8] = {x0.x, x0.y, x0.z, x0.w, x1.x, x1.y, x1.z, x1.w};
            #pragma unroll
            for (int j = 0; j < 8; ++j){
                acc[0][j] += w.x * xv[j];
                acc[1][j] += w.y * xv[j];
            }
        }
        __syncthreads();
    }

    // epilogue: +b_v2, write lred, per-b wave-butterfly softmax stats
    const int  va    = v0 + lane * 2;       // even; VO even -> pairs never split
    const bool valid = va < VO;
    float b2a = 0.f, b2b = 0.f;
    if (valid){ float2 bb = *(const float2*)&b2[va]; b2a = bb.x; b2b = bb.y; }

    #pragma unroll
    for (int j = 0; j < 8; ++j){
        const int b = b0 + j;
        float m, s;
        if (valid){
            float la = acc[0][j] + b2a;
            float lb = acc[1][j] + b2b;
            *(float2*)&lred[(size_t)b * VO + va] = make_float2(la, lb);
            m = fmaxf(la, lb);
            s = __expf(la - m) + __expf(lb - m);
        } else { m = -1e30f; s = 0.f; }
        #pragma unroll
        for (int off = 1; off < 64; off <<= 1){
            float m2 = __shfl_xor(m, off, 64);
            float s2 = __shfl_xor(s, off, 64);
            float M  = fmaxf(m, m2);
            s = s * __expf(m - M) + s2 * __expf(m2 - M);
            m = M;
        }
        if (lane == 0){
            mch[b * NCHV + blockIdx.x] = m;
            sch[b * NCHV + blockIdx.x] = s;
        }
    }
}

// K2a: attn logit[b][s] = sum_d tanh(enc1[b][s][d] + dec_op1[b][d] + b_dec[d]) * w_attn[d]
__global__ void k2a_logit(const float* __restrict__ enc1, const float* __restrict__ dop1,
                          const float* __restrict__ bdec, const float* __restrict__ wat,
                          float* __restrict__ lg){
    int b = blockIdx.x;
    int wave = threadIdx.x >> 6, lane = threadIdx.x & 63;
    int s0 = blockIdx.y * 16 + wave * 4;
    __shared__ float sd[D2], sw[D2];
    for (int i = threadIdx.x; i < D2; i += 256){
        sd[i] = dop1[b * D2 + i] + bdec[i];
        sw[i] = wat[i];
    }
    __syncthreads();
    const float4* sd4 = (const float4*)sd;
    const float4* sw4 = (const float4*)sw;
    for (int r = 0; r < 4; ++r){
        int s = s0 + r;
        const float4* row = (const float4*)(enc1 + ((size_t)b * S + s) * D2);
        float acc = 0.f;
        #pragma unroll
        for (int i = 0; i < 4; ++i){
            int k4 = i * 64 + lane;
            float4 e = row[k4]; float4 dv = sd4[k4]; float4 wv = sw4[k4];
            acc += fast_tanh(e.x + dv.x) * wv.x + fast_tanh(e.y + dv.y) * wv.y
                 + fast_tanh(e.z + dv.z) * wv.z + fast_tanh(e.w + dv.w) * wv.w;
        }
        #pragma unroll
        for (int off = 32; off > 0; off >>= 1) acc += __shfl_down(acc, off, 64);
        if (lane == 0) lg[b * S + s] = acc;
    }
}

// K2b: masked softmax + renormalize -> attn (output 1)
__global__ void k2b_attnsm(const float* __restrict__ lg, const int* __restrict__ src,
                           float* __restrict__ attn){
    int b = blockIdx.x, t = threadIdx.x;
    __shared__ float red[256];
    float l[4];
    float m = -1e30f;
    #pragma unroll
    for (int i = 0; i < 4; ++i){ l[i] = lg[b * S + t + i * 256]; m = fmaxf(m, l[i]); }
    red[t] = m; __syncthreads();
    for (int o = 128; o > 0; o >>= 1){
        if (t < o) red[t] = fmaxf(red[t], red[t + o]);
        __syncthreads();
    }
    m = red[0]; __syncthreads();
    float e[4]; float sum = 0.f;
    #pragma unroll
    for (int i = 0; i < 4; ++i){
        int s = t + i * 256;
        bool keep = src[b * S + s] != 0;
        e[i] = keep ? __expf(l[i] - m) : 0.f;
        sum += e[i];
    }
    red[t] = sum; __syncthreads();
    for (int o = 128; o > 0; o >>= 1){
        if (t < o) red[t] += red[t + o];
        __syncthreads();
    }
    float inv = 1.0f / red[0];
    #pragma unroll
    for (int i = 0; i < 4; ++i) attn[b * S + t + i * 256] = e[i] * inv;
}

// K2c: context partials over s-splits
__global__ void k2c_ctxpart(const float* __restrict__ enc, const float* __restrict__ attn,
                            float* __restrict__ part){
    int b = blockIdx.x, sp = blockIdx.y, t = threadIdx.x;
    __shared__ float sa[32];
    if (t < 32) sa[t] = attn[b * S + sp * 32 + t];
    __syncthreads();
    const float4* base = (const float4*)(enc + ((size_t)b * S + sp * 32) * D2);
    float4 acc = make_float4(0.f, 0.f, 0.f, 0.f);
    #pragma unroll 4
    for (int s = 0; s < 32; ++s){
        float a = sa[s];
        float4 e = base[s * (D2 / 4) + t];
        acc.x += a * e.x; acc.y += a * e.y; acc.z += a * e.z; acc.w += a * e.w;
    }
    ((float4*)(part + ((size_t)(b * 32 + sp)) * D2))[t] = acc;
}

// K2d: reduce partials + batchnorm -> context (output 2)
__global__ void k2d_ctxbn(const float* __restrict__ part, const float* __restrict__ gamma,
                          const float* __restrict__ beta, const float* __restrict__ mean,
                          const float* __restrict__ var, float* __restrict__ ctx){
    int b = blockIdx.x, t = threadIdx.x;
    float4 acc = make_float4(0.f, 0.f, 0.f, 0.f);
    for (int sp = 0; sp < 32; ++sp){
        float4 p = ((const float4*)(part + ((size_t)(b * 32 + sp)) * D2))[t];
        acc.x += p.x; acc.y += p.y; acc.z += p.z; acc.w += p.w;
    }
    float4 g  = ((const float4*)gamma)[t];
    float4 be = ((const float4*)beta)[t];
    float4 mn = ((const float4*)mean)[t];
    float4 vr = ((const float4*)var)[t];
    acc.x = (acc.x - mn.x) * rsqrtf(vr.x + 1e-5f) * g.x + be.x;
    acc.y = (acc.y - mn.y) * rsqrtf(vr.y + 1e-5f) * g.y + be.y;
    acc.z = (acc.z - mn.z) * rsqrtf(vr.z + 1e-5f) * g.z + be.z;
    acc.w = (acc.w - mn.w) * rsqrtf(vr.w + 1e-5f) * g.w + be.w;
    ((float4*)(ctx + (size_t)b * D2))[t] = acc;
}

// K3b: p_gen[b] = sigmoid([ctx;h;c;dec_inp] . W_p + b_p)
__global__ void k3b_pgen(const float* __restrict__ ctx, const float* __restrict__ h,
                         const float* __restrict__ c, const float* __restrict__ di,
                         const float* __restrict__ Wp, const float* __restrict__ bp,
                         float* __restrict__ pg){
    int b = blockIdx.x, t = threadIdx.x;
    float acc = 0.f;
    for (int k = t; k < D5; k += 256){
        float x;
        if (k < D2)            x = ctx[b * D2 + k];
        else if (k < D2 + D)   x = h[b * D + (k - D2)];
        else if (k < 2 * D2)   x = c[b * D + (k - D2 - D)];
        else                   x = di[b * D + (k - 2 * D2)];
        acc += x * Wp[k];
    }
    __shared__ float red[256];
    red[t] = acc; __syncthreads();
    for (int o = 128; o > 0; o >>= 1){
        if (t < o) red[t] += red[t + o];
        __syncthreads();
    }
    if (t == 0){
        float z = red[0] + bp[0];
        pg[b] = 1.0f / (1.0f + __expf(-z));
    }
}

// kB: combine chunk stats -> M[b], scale[b] = pg[b]/S[b]. One block per b.
__global__ void kB_comb(const float* __restrict__ mch, const float* __restrict__ sch,
                        const float* __restrict__ pg, float* __restrict__ Mb,
                        float* __restrict__ scaleb){
    int b = blockIdx.x, t = threadIdx.x;   // 128 threads
    float m = -1e30f, s = 0.f;
    for (int c = t; c < NCHV; c += 128){
        float mc = mch[b * NCHV + c], sc = sch[b * NCHV + c];
        float M = fmaxf(m, mc);
        s = s * __expf(m - M) + sc * __expf(mc - M);
        m = M;
    }
    __shared__ float sm[128], ss[128];
    sm[t] = m; ss[t] = s; __syncthreads();
    for (int o = 64; o > 0; o >>= 1){
        if (t < o){
            float m1 = sm[t], m2 = sm[t + o];
            float M = fmaxf(m1, m2);
            ss[t] = ss[t] * __expf(m1 - M) + ss[t + o] * __expf(m2 - M);
            sm[t] = M;
        }
        __syncthreads();
    }
    if (t == 0){
        Mb[b] = sm[0];
        scaleb[b] = pg[b] / ss[0];
    }
}

// kC: pf[b][v] = scale[b] * exp(lred - M[b]); chunk NCH zero-fills the OOV pad
__global__ void kC_final(const float* __restrict__ lred, const float* __restrict__ Mb,
                         const float* __restrict__ scaleb, float* __restrict__ pf){
    int b = blockIdx.x, c = blockIdx.y, t = threadIdx.x;
    if (c == NCH){
        for (int v = VO + t; v < V; v += 256) pf[(size_t)b * V + v] = 0.f;
        return;
    }
    float M = Mb[b], sc = scaleb[b];
    for (int v = c * CHW + t; v < (c + 1) * CHW; v += 256)
        pf[(size_t)b * V + v] = sc * __expf(lred[(size_t)b * VO + v] - M);
}

// K5b: scatter add (1-p_gen)*attn at src indices (32K atomics — negligible)
__global__ void k5b_scatter(const int* __restrict__ src, const float* __restrict__ attn,
                            const float* __restrict__ pg, float* __restrict__ pf){
    int b = blockIdx.x, t = threadIdx.x;
    float c1 = 1.0f - pg[b];
    for (int s = t; s < S; s += 256){
        int idx = src[b * S + s];
        atomicAdd(&pf[(size_t)b * V + idx], c1 * attn[b * S + s]);
    }
}

extern "C" void kernel_launch(void* const* d_in, const int* in_sizes, int n_in,
                              void* d_out, int out_size, void* d_ws, size_t ws_size,
                              hipStream_t stream){
    (void)in_sizes; (void)n_in; (void)out_size; (void)ws_size;
    const float* dec_output = (const float*)d_in[0];
    const float* h          = (const float*)d_in[1];
    const float* c          = (const float*)d_in[2];
    const float* dec_inp    = (const float*)d_in[3];
    const float* enc_op     = (const float*)d_in[4];
    const float* enc_op1    = (const float*)d_in[5];
    const int*   src        = (const int*)d_in[6];
    const float* W_dec      = (const float*)d_in[7];
    const float* b_dec      = (const float*)d_in[8];
    const float* w_attn     = (const float*)d_in[9];
    const float* W_v1       = (const float*)d_in[10];
    const float* b_v1       = (const float*)d_in[11];
    const float* W_v2       = (const float*)d_in[12];
    const float* b_v2       = (const float*)d_in[13];
    const float* W_p        = (const float*)d_in[14];
    const float* b_p        = (const float*)d_in[15];
    const float* bn_g       = (const float*)d_in[16];
    const float* bn_b       = (const float*)d_in[17];
    const float* bn_m       = (const float*)d_in[18];
    const float* bn_v       = (const float*)d_in[19];

    float* ws = (float*)d_ws;
    float* p1       = ws;                    // 16*32768   = 524288
    float* dec_op1  = ws + 524288;           // 32768
    float* p3       = ws + 557056;           // 16*16384   = 262144
    float* hidden   = ws + 819200;           // 16384
    float* lred     = ws + 835584;           // 1568000
    float* attn_lg  = ws + 2403584;          // 32768
    float* ctx_part = ws + 2436352;          // 1048576
    float* pg       = ws + 3484928;          // 32
    float* mch      = ws + 3484960;          // 32*383 = 12256
    float* sch      = ws + 3497216;          // 12256
    float* Mb       = ws + 3509472;          // 32
    float* scaleb   = ws + 3509504;          // 32   (total ~14 MB)

    float* pf   = (float*)d_out;             // [32,50000]
    float* attn = pf + 1600000;              // [32,1024]
    float* ctx  = pf + 1632768;              // [32,1024]

    // k1: dec_op1 = [h;c] @ W_dec^T  (b_dec folded into k2a)
    gemm_nt <<<dim3(4, 16),  256, 0, stream>>>(W_dec, D2, D2, h, c, D, D, D, p1, 64);
    kreduce <<<128,          256, 0, stream>>>(p1, dec_op1, B * D2, 16, nullptr, 0);
    k2a_logit<<<dim3(B, 64), 256, 0, stream>>>(enc_op1, dec_op1, b_dec, w_attn, attn_lg);
    k2b_attnsm<<<B,          256, 0, stream>>>(attn_lg, src, attn);
    k2c_ctxpart<<<dim3(B, 32), 256, 0, stream>>>(enc_op, attn, ctx_part);
    k2d_ctxbn<<<B,           256, 0, stream>>>(ctx_part, bn_g, bn_b, bn_m, bn_v, ctx);
    // k3: hidden = [dec_output;ctx] @ W_v1^T + b_v1 (bias in kreduce)
    gemm_nt <<<dim3(2, 16),  256, 0, stream>>>(W_v1, D, D + D2, dec_output, ctx,
                                               D, D, D2, p3, 96);
    kreduce <<<64,           256, 0, stream>>>(p3, hidden, B * D, 16, b_v1, D - 1);
    k3b_pgen<<<B,            256, 0, stream>>>(ctx, h, c, dec_inp, W_p, b_p, pg);
    // k4: lred = hidden @ W_v2^T + b_v2, fused chunk softmax stats
    gemm_vocab<<<NCHV,       256, 0, stream>>>(W_v2, hidden, b_v2, lred, mch, sch);
    kB_comb <<<B,            128, 0, stream>>>(mch, sch, pg, Mb, scaleb);
    kC_final<<<dim3(B, NCH + 1), 256, 0, stream>>>(lred, Mb, scaleb, pf);
    k5b_scatter<<<B,         256, 0, stream>>>(src, attn, pg, pf);
    // k5c (eps 1e-12) dropped: below 9e-3 absmax threshold by 9 orders of magnitude
}